// Round 2
// baseline (227.663 us; speedup 1.0000x reference)
//
#include <hip/hip_runtime.h>
#include <hip/hip_cooperative_groups.h>
#include <math.h>

namespace cg = cooperative_groups;

// Gaussian splatting forward rasterizer, MI355X.
// P=2048 gaussians, 128x128 image. Output: img (3*128*128 f32) ++ radii (P f32).
//
// R7 (this round): single cooperative kernel. R6's three dispatches
// (prep_rank_scatter -> raster_chunk -> combine) summed to ~10us of real work
// but paid 3 launch/drain boundaries in the timed window; counters show the
// only heavy dispatch is the harness's 39us/256MiB workspace-poison fill.
// Fused: one hipLaunchCooperativeKernel, grid.sync() between phases.
//   grid = 512 blocks (K=8 chunks x 64 tiles), __launch_bounds__(256,2)
//   -> 2 blocks/CU co-residency (LDS 9.25KB, low VGPR): safe for coop launch.
// K=16->8 halves the part-buffer round trip. All phase math is verbatim R6
// (absmax was 0.0).

#define IMG 128
#define NPIX (IMG * IMG)
#define GS 12        // record: px py ca cb cc op r g b r2 pad pad
#define SORT_N 2048
#define KCH 8        // chunks
#define GRID (64 * KCH)

// ---------------------------------------------------------- projection chain
__device__ __forceinline__ void gproj(int i,
                                      const float* __restrict__ means,
                                      const float* __restrict__ rots,
                                      const float* __restrict__ scales,
                                      const float* __restrict__ vm,
                                      const float* __restrict__ pm,
                                      float& depth, bool& valid,
                                      float& px, float& py,
                                      float& ca, float& cb, float& cc,
                                      float& lam)
{
    const float W = (float)IMG, H = (float)IMG;
    const float tanfov = 0.5773502691896258f;        // tan(FOV/2)
    const float focal_x = W / (2.0f * tanfov);
    const float focal_y = H / (2.0f * tanfov);
    const float lim = 1.3f * tanfov;

    float mx = means[3 * i + 0], my = means[3 * i + 1], mz = means[3 * i + 2];

    float tx = vm[0] * mx + vm[1] * my + vm[2]  * mz + vm[3];
    float ty = vm[4] * mx + vm[5] * my + vm[6]  * mz + vm[7];
    float tz = vm[8] * mx + vm[9] * my + vm[10] * mz + vm[11];
    depth = tz;

    float ph0 = pm[0]  * mx + pm[1]  * my + pm[2]  * mz + pm[3];
    float ph1 = pm[4]  * mx + pm[5]  * my + pm[6]  * mz + pm[7];
    float pw  = pm[12] * mx + pm[13] * my + pm[14] * mz + pm[15];
    float rinv = 1.0f / (pw + 1e-7f);
    px = ((ph0 * rinv + 1.0f) * W - 1.0f) * 0.5f;
    py = ((ph1 * rinv + 1.0f) * H - 1.0f) * 0.5f;

    float qw = rots[4 * i + 0], qx = rots[4 * i + 1], qy = rots[4 * i + 2], qz = rots[4 * i + 3];
    float qn = sqrtf(qw * qw + qx * qx + qy * qy + qz * qz);
    qw /= qn; qx /= qn; qy /= qn; qz /= qn;
    float R00 = 1.0f - 2.0f * (qy * qy + qz * qz), R01 = 2.0f * (qx * qy - qw * qz), R02 = 2.0f * (qx * qz + qw * qy);
    float R10 = 2.0f * (qx * qy + qw * qz), R11 = 1.0f - 2.0f * (qx * qx + qz * qz), R12 = 2.0f * (qy * qz - qw * qx);
    float R20 = 2.0f * (qx * qz - qw * qy), R21 = 2.0f * (qy * qz + qw * qx), R22 = 1.0f - 2.0f * (qx * qx + qy * qy);

    float sx = scales[3 * i + 0], sy = scales[3 * i + 1], sz = scales[3 * i + 2];
    float M00 = R00 * sx, M01 = R01 * sy, M02 = R02 * sz;
    float M10 = R10 * sx, M11 = R11 * sy, M12 = R12 * sz;
    float M20 = R20 * sx, M21 = R21 * sy, M22 = R22 * sz;
    float S00 = M00 * M00 + M01 * M01 + M02 * M02;
    float S01 = M00 * M10 + M01 * M11 + M02 * M12;
    float S02 = M00 * M20 + M01 * M21 + M02 * M22;
    float S11 = M10 * M10 + M11 * M11 + M12 * M12;
    float S12 = M10 * M20 + M11 * M21 + M12 * M22;
    float S22 = M20 * M20 + M21 * M21 + M22 * M22;

    float txc = fminf(fmaxf(tx / tz, -lim), lim) * tz;
    float tyc = fminf(fmaxf(ty / tz, -lim), lim) * tz;
    float J00 = focal_x / tz, J02 = -focal_x * txc / (tz * tz);
    float J11 = focal_y / tz, J12 = -focal_y * tyc / (tz * tz);

    float T00 = J00 * vm[0] + J02 * vm[8];
    float T01 = J00 * vm[1] + J02 * vm[9];
    float T02 = J00 * vm[2] + J02 * vm[10];
    float T10 = J11 * vm[4] + J12 * vm[8];
    float T11 = J11 * vm[5] + J12 * vm[9];
    float T12 = J11 * vm[6] + J12 * vm[10];

    float U00 = T00 * S00 + T01 * S01 + T02 * S02;
    float U01 = T00 * S01 + T01 * S11 + T02 * S12;
    float U02 = T00 * S02 + T01 * S12 + T02 * S22;
    float U10 = T10 * S00 + T11 * S01 + T12 * S02;
    float U11 = T10 * S01 + T11 * S11 + T12 * S12;
    float U12 = T10 * S02 + T11 * S12 + T12 * S22;
    float C00 = U00 * T00 + U01 * T01 + U02 * T02;
    float C01 = U00 * T10 + U01 * T11 + U02 * T12;
    float C11 = U10 * T10 + U11 * T11 + U12 * T12;

    float a = C00 + 0.3f, b = C01, c = C11 + 0.3f;
    float det = a * c - b * b;
    valid = (depth > 0.2f) && (det > 0.0f);
    float det_s = valid ? det : 1.0f;
    ca = c / det_s; cb = -b / det_s; cc = a / det_s;

    float mid = 0.5f * (a + c);
    lam = mid + sqrtf(fmaxf(mid * mid - det, 0.1f));
}

// ---------------------------------------------------- fused cooperative kernel
__global__ void __launch_bounds__(256, 2)
gsplat_fused(const float* __restrict__ means,
             const float* __restrict__ feats,
             const float* __restrict__ ops,
             const float* __restrict__ scales,
             const float* __restrict__ rots,
             const float* __restrict__ vm,
             const float* __restrict__ pm,
             float* __restrict__ gS,
             float4* __restrict__ culls,
             float* __restrict__ radii_out,
             float4* __restrict__ part,
             float* __restrict__ img,
             int P, int chunk)
{
    __shared__ unsigned int sk[SORT_N];
    __shared__ int partial[256];
    int tid = threadIdx.x;
    cg::grid_group grid = cg::this_grid();

    // ============================ Phase 1: prep + rank + scatter (blocks 0..31)
    if (blockIdx.x < (SORT_N + 63) / 64) {
        // Phase A: depth-only sort keys. valid == depth>0.2 (det>0 always:
        // det = (C00+.3)(C11+.3)-C01^2 >= .3(C00+C11)+.09, cov2d PSD; the
        // margin is ~1e3 vs fp32 error ~1e-3, in the reference too).
        #pragma unroll 2
        for (int j = tid; j < SORT_N; j += 256) {
            unsigned int key = 0xFFFFFFFFu;              // pad sorts last
            if (j < P) {
                float mx = means[3 * j + 0], my = means[3 * j + 1], mz = means[3 * j + 2];
                float tz = vm[8] * mx + vm[9] * my + vm[10] * mz + vm[11];
                key = (tz > 0.2f) ? __float_as_uint(tz) : 0x7f800000u;
            }
            sk[j] = key;
        }
        __syncthreads();

        // Phase B: stable rank for this block's 64 gaussians (4 slices x 64).
        int g = tid & 63, s = tid >> 6;
        int i = blockIdx.x * 64 + g;
        bool act = (i < P);
        unsigned int ki = act ? sk[i] : 0u;

        const int SLICE = SORT_N / 4;
        int j0 = s * SLICE;
        const uint4* sk4 = (const uint4*)(sk + j0);
        int r = 0;
        #pragma unroll 4
        for (int q = 0; q < SLICE / 4; ++q) {
            uint4 k = sk4[q];                            // wave-broadcast
            int j = j0 + 4 * q;
            r += (k.x < ki) || (k.x == ki && (j + 0) < i);
            r += (k.y < ki) || (k.y == ki && (j + 1) < i);
            r += (k.z < ki) || (k.z == ki && (j + 2) < i);
            r += (k.w < ki) || (k.w == ki && (j + 3) < i);
        }
        partial[tid] = r;
        __syncthreads();

        // Phase C: full record -> sorted slot; radii in original order.
        if (s == 0 && act) {
            int rank = partial[g] + partial[64 + g] + partial[128 + g] + partial[192 + g];

            float depth, px, py, ca, cb, cc, lam; bool valid;
            gproj(i, means, rots, scales, vm, pm, depth, valid, px, py, ca, cb, cc, lam);

            const float SH_C0 = 0.28209479177387814f;
            float colr = fmaxf(SH_C0 * feats[3 * i + 0] + 0.5f, 0.0f);
            float colg = fmaxf(SH_C0 * feats[3 * i + 1] + 0.5f, 0.0f);
            float colb = fmaxf(SH_C0 * feats[3 * i + 2] + 0.5f, 0.0f);

            float opv = ops[i];
            float r2;
            if (valid) {
                // alpha >= 1/255 requires d^2 <= 2*lam_max*ln(255*op)
                r2 = 2.0f * lam * __logf(255.0f * opv) * 1.02f + 0.5f;
            } else {
                px = 0.0f; py = 0.0f; ca = 0.0f; cb = 0.0f; cc = 0.0f;
                opv = 0.0f; r2 = -1.0f;                  // never composited
            }
            radii_out[i] = valid ? ceilf(3.0f * sqrtf(lam)) : 0.0f;

            float4* dst = (float4*)(gS + (size_t)rank * GS);
            dst[0] = make_float4(px, py, ca, cb);
            dst[1] = make_float4(cc, opv, colr, colg);
            dst[2] = make_float4(colb, r2, 0.0f, 0.0f);
            culls[rank] = make_float4(px, py, r2, 0.0f); // compact cull record
        }
    }

    grid.sync();

    // ============================ Phase 2: chunked raster (all 512 blocks)
    {
        int tile = blockIdx.x & 63;
        int kc = blockIdx.x >> 6;                        // chunk index 0..KCH-1
        int lx = tid & 15, ly = tid >> 4;
        int lane = tid & 63;
        int tilex = tile & 7, tiley = tile >> 3;
        int x = tilex * 16 + lx, y = tiley * 16 + ly;
        float gx = (float)x, gy = (float)y;
        float tx0 = (float)(tilex * 16), tx1 = (float)(tilex * 16 + 15);
        float ty0 = (float)(tiley * 16), ty1 = (float)(tiley * 16 + 15);

        int base = kc * chunk;
        int cnt = min(chunk, P - base);

        float T = 1.0f, cr = 0.0f, cgc = 0.0f, cbl = 0.0f;
        const float* Gp = gS + (size_t)base * GS;

        for (int h = 0; h < chunk; h += 64) {
            int gi = h + lane;
            bool pred = false;
            if (gi < cnt) {
                float4 cu = culls[base + gi];
                float ddx = cu.x - fminf(fmaxf(cu.x, tx0), tx1);
                float ddy = cu.y - fminf(fmaxf(cu.y, ty0), ty1);
                pred = (ddx * ddx + ddy * ddy <= cu.z);
            }
            unsigned long long m = __ballot(pred);       // wave-uniform mask
            while (m) {
                int b = __builtin_ctzll(m);              // ascending rank
                m &= m - 1;
                const float4* G4 = (const float4*)(Gp + (size_t)(h + b) * GS);
                float4 A = G4[0], B = G4[1], C = G4[2];
                float dx = gx - A.x, dy = gy - A.y;
                float power = -0.5f * (A.z * dx * dx + B.x * dy * dy) - A.w * dx * dy;
                float e = __expf(fminf(power, 0.0f));
                float alpha = fminf(0.99f, B.y * e);
                alpha = (power > 0.0f) ? 0.0f : alpha;
                alpha = (alpha < 0.00392156862745098f) ? 0.0f : alpha;
                float w = T * alpha;
                cr  = fmaf(w, B.z, cr);
                cgc = fmaf(w, B.w, cgc);
                cbl = fmaf(w, C.x, cbl);
                T = T * (1.0f - alpha);
            }
        }

        int pix = y * IMG + x;
        part[(size_t)kc * NPIX + pix] = make_float4(cr, cgc, cbl, T);
    }

    grid.sync();

    // ============================ Phase 3: ordered combine (blocks 0..63)
    if (blockIdx.x < NPIX / 256) {
        int pix = blockIdx.x * 256 + tid;
        float T = 1.0f, r = 0.0f, g = 0.0f, b = 0.0f;
        #pragma unroll
        for (int c = 0; c < KCH; ++c) {
            float4 v = part[(size_t)c * NPIX + pix];
            r = fmaf(T, v.x, r);
            g = fmaf(T, v.y, g);
            b = fmaf(T, v.z, b);
            T *= v.w;
        }
        img[pix]            = r + T;
        img[NPIX + pix]     = g + T;
        img[2 * NPIX + pix] = b + T;
    }
}

// ------------------------------------------------------------------ launch
extern "C" void kernel_launch(void* const* d_in, const int* in_sizes, int n_in,
                              void* d_out, int out_size, void* d_ws, size_t ws_size,
                              hipStream_t stream)
{
    const float* means  = (const float*)d_in[0];
    const float* feats  = (const float*)d_in[2];
    const float* ops    = (const float*)d_in[3];
    const float* scales = (const float*)d_in[4];
    const float* rots   = (const float*)d_in[5];
    const float* vm     = (const float*)d_in[6];
    const float* pm     = (const float*)d_in[7];

    int P = in_sizes[0] / 3;   // 2048

    float* img   = (float*)d_out;            // 3*128*128
    float* radii = (float*)d_out + 3 * NPIX; // P

    float*  gS    = (float*)d_ws;                        // SORT_N*GS floats
    float4* culls = (float4*)(gS + (size_t)SORT_N * GS); // SORT_N float4
    float4* part  = culls + SORT_N;                      // KCH*NPIX float4

    int chunk = (P + KCH - 1) / KCH;
    chunk = (chunk + 63) & ~63;              // h-loop walks 64-gaussian groups

    void* args[] = {
        (void*)&means, (void*)&feats, (void*)&ops, (void*)&scales,
        (void*)&rots,  (void*)&vm,    (void*)&pm,
        (void*)&gS, (void*)&culls, (void*)&radii, (void*)&part, (void*)&img,
        (void*)&P, (void*)&chunk
    };
    hipLaunchCooperativeKernel((void*)gsplat_fused, dim3(GRID), dim3(256),
                               args, 0, stream);
}

// Round 3
// 141.485 us; speedup vs baseline: 1.6091x; 1.6091x over previous
//
#include <hip/hip_runtime.h>
#include <math.h>

// Gaussian splatting forward rasterizer, MI355X.
// P=2048 gaussians, 128x128 image. Output: img (3*128*128 f32) ++ radii (P f32).
//
// R8: revert R7's cooperative fusion (grid.sync() = ~65us device-atomic spin
// per barrier on gfx950 -> 133us kernel, VALUBusy 1.5%). Back to separate
// dispatches, but 2 instead of R6's 3:
//   1) prep_rank_scatter (32 blocks): depth-key rank + record scatter (R6).
//   2) raster_full (64 tile blocks): stages ALL records into LDS (128 KB,
//      1 block/CU), ballot-culls 64 gaussians/wave-iter, composites the full
//      sorted list front-to-back, writes img directly.
// Eliminates the part-buffer round trip and the combine dispatch. Full
// sequential compositing reproduces the reference cumprod order exactly.

#define IMG 128
#define NPIX (IMG * IMG)
#define GS 12        // record: px py ca cb cc op r g b r2 pad pad
#define SORT_N 2048

// ---------------------------------------------------------- projection chain
__device__ __forceinline__ void gproj(int i,
                                      const float* __restrict__ means,
                                      const float* __restrict__ rots,
                                      const float* __restrict__ scales,
                                      const float* __restrict__ vm,
                                      const float* __restrict__ pm,
                                      float& depth, bool& valid,
                                      float& px, float& py,
                                      float& ca, float& cb, float& cc,
                                      float& lam)
{
    const float W = (float)IMG, H = (float)IMG;
    const float tanfov = 0.5773502691896258f;        // tan(FOV/2)
    const float focal_x = W / (2.0f * tanfov);
    const float focal_y = H / (2.0f * tanfov);
    const float lim = 1.3f * tanfov;

    float mx = means[3 * i + 0], my = means[3 * i + 1], mz = means[3 * i + 2];

    float tx = vm[0] * mx + vm[1] * my + vm[2]  * mz + vm[3];
    float ty = vm[4] * mx + vm[5] * my + vm[6]  * mz + vm[7];
    float tz = vm[8] * mx + vm[9] * my + vm[10] * mz + vm[11];
    depth = tz;

    float ph0 = pm[0]  * mx + pm[1]  * my + pm[2]  * mz + pm[3];
    float ph1 = pm[4]  * mx + pm[5]  * my + pm[6]  * mz + pm[7];
    float pw  = pm[12] * mx + pm[13] * my + pm[14] * mz + pm[15];
    float rinv = 1.0f / (pw + 1e-7f);
    px = ((ph0 * rinv + 1.0f) * W - 1.0f) * 0.5f;
    py = ((ph1 * rinv + 1.0f) * H - 1.0f) * 0.5f;

    float qw = rots[4 * i + 0], qx = rots[4 * i + 1], qy = rots[4 * i + 2], qz = rots[4 * i + 3];
    float qn = sqrtf(qw * qw + qx * qx + qy * qy + qz * qz);
    qw /= qn; qx /= qn; qy /= qn; qz /= qn;
    float R00 = 1.0f - 2.0f * (qy * qy + qz * qz), R01 = 2.0f * (qx * qy - qw * qz), R02 = 2.0f * (qx * qz + qw * qy);
    float R10 = 2.0f * (qx * qy + qw * qz), R11 = 1.0f - 2.0f * (qx * qx + qz * qz), R12 = 2.0f * (qy * qz - qw * qx);
    float R20 = 2.0f * (qx * qz - qw * qy), R21 = 2.0f * (qy * qz + qw * qx), R22 = 1.0f - 2.0f * (qx * qx + qy * qy);

    float sx = scales[3 * i + 0], sy = scales[3 * i + 1], sz = scales[3 * i + 2];
    float M00 = R00 * sx, M01 = R01 * sy, M02 = R02 * sz;
    float M10 = R10 * sx, M11 = R11 * sy, M12 = R12 * sz;
    float M20 = R20 * sx, M21 = R21 * sy, M22 = R22 * sz;
    float S00 = M00 * M00 + M01 * M01 + M02 * M02;
    float S01 = M00 * M10 + M01 * M11 + M02 * M12;
    float S02 = M00 * M20 + M01 * M21 + M02 * M22;
    float S11 = M10 * M10 + M11 * M11 + M12 * M12;
    float S12 = M10 * M20 + M11 * M21 + M12 * M22;
    float S22 = M20 * M20 + M21 * M21 + M22 * M22;

    float txc = fminf(fmaxf(tx / tz, -lim), lim) * tz;
    float tyc = fminf(fmaxf(ty / tz, -lim), lim) * tz;
    float J00 = focal_x / tz, J02 = -focal_x * txc / (tz * tz);
    float J11 = focal_y / tz, J12 = -focal_y * tyc / (tz * tz);

    float T00 = J00 * vm[0] + J02 * vm[8];
    float T01 = J00 * vm[1] + J02 * vm[9];
    float T02 = J00 * vm[2] + J02 * vm[10];
    float T10 = J11 * vm[4] + J12 * vm[8];
    float T11 = J11 * vm[5] + J12 * vm[9];
    float T12 = J11 * vm[6] + J12 * vm[10];

    float U00 = T00 * S00 + T01 * S01 + T02 * S02;
    float U01 = T00 * S01 + T01 * S11 + T02 * S12;
    float U02 = T00 * S02 + T01 * S12 + T02 * S22;
    float U10 = T10 * S00 + T11 * S01 + T12 * S02;
    float U11 = T10 * S01 + T11 * S11 + T12 * S12;
    float U12 = T10 * S02 + T11 * S12 + T12 * S22;
    float C00 = U00 * T00 + U01 * T01 + U02 * T02;
    float C01 = U00 * T10 + U01 * T11 + U02 * T12;
    float C11 = U10 * T10 + U11 * T11 + U12 * T12;

    float a = C00 + 0.3f, b = C01, c = C11 + 0.3f;
    float det = a * c - b * b;
    valid = (depth > 0.2f) && (det > 0.0f);
    float det_s = valid ? det : 1.0f;
    ca = c / det_s; cb = -b / det_s; cc = a / det_s;

    float mid = 0.5f * (a + c);
    lam = mid + sqrtf(fmaxf(mid * mid - det, 0.1f));
}

// ------------------------------------------- fused preprocess + rank + scatter
__global__ void gsplat_prep_rank_scatter(const float* __restrict__ means,
                                         const float* __restrict__ feats,
                                         const float* __restrict__ ops,
                                         const float* __restrict__ scales,
                                         const float* __restrict__ rots,
                                         const float* __restrict__ vm,
                                         const float* __restrict__ pm,
                                         float* __restrict__ gS,
                                         float4* __restrict__ culls,
                                         float* __restrict__ radii_out,
                                         int P)
{
    __shared__ unsigned int sk[SORT_N];
    __shared__ int partial[256];
    int tid = threadIdx.x;

    // Phase A: depth-only sort keys. valid == depth>0.2 (det>0 always:
    // det = (C00+.3)(C11+.3)-C01^2 >= .3(C00+C11)+.09, cov2d PSD; margin
    // ~1e3 vs fp32 error ~1e-3 -- holds in the reference too).
    #pragma unroll 2
    for (int j = tid; j < SORT_N; j += 256) {
        unsigned int key = 0xFFFFFFFFu;                  // pad sorts last
        if (j < P) {
            float mx = means[3 * j + 0], my = means[3 * j + 1], mz = means[3 * j + 2];
            float tz = vm[8] * mx + vm[9] * my + vm[10] * mz + vm[11];
            key = (tz > 0.2f) ? __float_as_uint(tz) : 0x7f800000u; // +inf invalid
        }
        sk[j] = key;
    }
    __syncthreads();

    // Phase B: stable rank for this block's 64 gaussians (4 key-slices x 64).
    int g = tid & 63, s = tid >> 6;
    int i = blockIdx.x * 64 + g;
    bool act = (i < P);
    unsigned int ki = act ? sk[i] : 0u;

    const int SLICE = SORT_N / 4;
    int j0 = s * SLICE;
    const uint4* sk4 = (const uint4*)(sk + j0);
    int r = 0;
    #pragma unroll 4
    for (int q = 0; q < SLICE / 4; ++q) {
        uint4 k = sk4[q];                                // wave-broadcast
        int j = j0 + 4 * q;
        r += (k.x < ki) || (k.x == ki && (j + 0) < i);
        r += (k.y < ki) || (k.y == ki && (j + 1) < i);
        r += (k.z < ki) || (k.z == ki && (j + 2) < i);
        r += (k.w < ki) || (k.w == ki && (j + 3) < i);
    }
    partial[tid] = r;
    __syncthreads();

    // Phase C: full record for own gaussian -> sorted slot; radii in orig order.
    if (s == 0 && act) {
        int rank = partial[g] + partial[64 + g] + partial[128 + g] + partial[192 + g];

        float depth, px, py, ca, cb, cc, lam; bool valid;
        gproj(i, means, rots, scales, vm, pm, depth, valid, px, py, ca, cb, cc, lam);

        const float SH_C0 = 0.28209479177387814f;
        float colr = fmaxf(SH_C0 * feats[3 * i + 0] + 0.5f, 0.0f);
        float colg = fmaxf(SH_C0 * feats[3 * i + 1] + 0.5f, 0.0f);
        float colb = fmaxf(SH_C0 * feats[3 * i + 2] + 0.5f, 0.0f);

        float opv = ops[i];
        float r2;
        if (valid) {
            // alpha >= 1/255 requires d^2 <= 2*lam_max*ln(255*op) (exact bound)
            r2 = 2.0f * lam * __logf(255.0f * opv) * 1.02f + 0.5f;
        } else {
            px = 0.0f; py = 0.0f; ca = 0.0f; cb = 0.0f; cc = 0.0f;
            opv = 0.0f; r2 = -1.0f;                      // never composited
        }
        radii_out[i] = valid ? ceilf(3.0f * sqrtf(lam)) : 0.0f;

        float4* dst = (float4*)(gS + (size_t)rank * GS);
        dst[0] = make_float4(px, py, ca, cb);
        dst[1] = make_float4(cc, opv, colr, colg);
        dst[2] = make_float4(colb, r2, 0.0f, 0.0f);
        culls[rank] = make_float4(px, py, r2, 0.0f);     // compact cull record
    }
}

// ----------------------------------------------------------------- raster
// 64 blocks (one per 16x16 tile), 256 threads (one per pixel). Stages the
// whole sorted record set into LDS (32 KB culls + 96 KB records = 128 KB ->
// 1 block/CU), then ballot-culls 64 gaussians per wave-iteration and
// composites only the hits, front-to-back over the FULL sorted list, writing
// img directly. No part buffer, no combine dispatch. Record reads in the
// bit-loop are wave-uniform LDS broadcasts (conflict-free).
__global__ void __launch_bounds__(256)
gsplat_raster_full(const float* __restrict__ gS,
                   const float4* __restrict__ culls,
                   int P, float* __restrict__ img)
{
    __shared__ float4 scull[SORT_N];          // 32 KB
    __shared__ float  srec[SORT_N * GS];      // 96 KB
    int tid = threadIdx.x;

    // Bulk coalesced stage; pad slots >= P with r2 = -1 (never hit).
    for (int j = tid; j < SORT_N; j += 256)
        scull[j] = (j < P) ? culls[j] : make_float4(0.0f, 0.0f, -1.0f, 0.0f);
    {
        const float4* g4 = (const float4*)gS;
        float4* s4 = (float4*)srec;
        int n4 = (P * GS) / 4;
        for (int j = tid; j < n4; j += 256) s4[j] = g4[j];
    }
    __syncthreads();

    int lx = tid & 15, ly = tid >> 4;
    int lane = tid & 63;
    int tilex = blockIdx.x & 7, tiley = blockIdx.x >> 3;
    int x = tilex * 16 + lx, y = tiley * 16 + ly;
    float gx = (float)x, gy = (float)y;
    float tx0 = (float)(tilex * 16), tx1 = (float)(tilex * 16 + 15);
    float ty0 = (float)(tiley * 16), ty1 = (float)(tiley * 16 + 15);

    float T = 1.0f, cr = 0.0f, cg = 0.0f, cb = 0.0f;

    #pragma unroll 2
    for (int h = 0; h < SORT_N; h += 64) {
        float4 cu = scull[h + lane];
        // nearest tile point vs r2 bound
        float ddx = cu.x - fminf(fmaxf(cu.x, tx0), tx1);
        float ddy = cu.y - fminf(fmaxf(cu.y, ty0), ty1);
        bool pred = (ddx * ddx + ddy * ddy <= cu.z);
        unsigned long long m = __ballot(pred);           // wave-uniform mask
        while (m) {
            int b = __builtin_ctzll(m);                  // ascending rank
            m &= m - 1;
            const float4* R4 = (const float4*)(srec + (size_t)(h + b) * GS);
            float4 A = R4[0], B = R4[1], C = R4[2];      // LDS broadcast
            float dx = gx - A.x, dy = gy - A.y;
            float power = -0.5f * (A.z * dx * dx + B.x * dy * dy) - A.w * dx * dy;
            float e = __expf(fminf(power, 0.0f));
            float alpha = fminf(0.99f, B.y * e);
            alpha = (power > 0.0f) ? 0.0f : alpha;
            alpha = (alpha < 0.00392156862745098f) ? 0.0f : alpha;
            float w = T * alpha;
            cr = fmaf(w, B.z, cr);
            cg = fmaf(w, B.w, cg);
            cb = fmaf(w, C.x, cb);
            T = T * (1.0f - alpha);
        }
    }

    int pix = y * IMG + x;
    img[pix]            = cr + T;
    img[NPIX + pix]     = cg + T;
    img[2 * NPIX + pix] = cb + T;
}

// ------------------------------------------------------------------ launch
extern "C" void kernel_launch(void* const* d_in, const int* in_sizes, int n_in,
                              void* d_out, int out_size, void* d_ws, size_t ws_size,
                              hipStream_t stream)
{
    const float* means  = (const float*)d_in[0];
    const float* feats  = (const float*)d_in[2];
    const float* ops    = (const float*)d_in[3];
    const float* scales = (const float*)d_in[4];
    const float* rots   = (const float*)d_in[5];
    const float* vm     = (const float*)d_in[6];
    const float* pm     = (const float*)d_in[7];

    int P = in_sizes[0] / 3;   // 2048

    float* img   = (float*)d_out;            // 3*128*128
    float* radii = (float*)d_out + 3 * NPIX; // P

    float*  gS    = (float*)d_ws;                        // SORT_N*GS floats
    float4* culls = (float4*)(gS + (size_t)SORT_N * GS); // SORT_N float4

    gsplat_prep_rank_scatter<<<(P + 63) / 64, 256, 0, stream>>>(
        means, feats, ops, scales, rots, vm, pm, gS, culls, radii, P);

    gsplat_raster_full<<<64, 256, 0, stream>>>(gS, culls, P, img);
}

// Round 4
// 104.223 us; speedup vs baseline: 2.1844x; 1.3575x over previous
//
#include <hip/hip_runtime.h>
#include <math.h>

// Gaussian splatting forward rasterizer, MI355X.
// P=2048 gaussians, 128x128 image. Output: img (3*128*128 f32) ++ radii (P f32).
//
// R9: back to the proven R6 3-dispatch structure (107us; R8's single-tile
// raster was latency-serial at 1% occupancy -> 56us kernel). Changes vs R6:
//  - raster bit-loop: 4-wide manual unroll. Per hit R6 paid a DEPENDENT
//    uniform global load (~250cyc) + ~60cyc math, serially. Now up to 4 hits'
//    record loads issue independently, alphas (T-independent) compute in
//    parallel, then 4 exact-order T-updates. Chain /3-4.
//  - cull loads: CHUNK=128 compile-time -> both 64-wide cull loads issue
//    up front (no loop-carried prefetch).
//  - combine: K=16 compile-time -> 16 independent loads fully unrolled.
// Compositing arithmetic and order are bit-identical to R6 (absmax 0.0).

#define IMG 128
#define NPIX (IMG * IMG)
#define GS 12        // record: px py ca cb cc op r g b r2 pad pad
#define SORT_N 2048
#define KCH 16
#define CHUNK (SORT_N / KCH)   // 128

// ---------------------------------------------------------- projection chain
__device__ __forceinline__ void gproj(int i,
                                      const float* __restrict__ means,
                                      const float* __restrict__ rots,
                                      const float* __restrict__ scales,
                                      const float* __restrict__ vm,
                                      const float* __restrict__ pm,
                                      float& depth, bool& valid,
                                      float& px, float& py,
                                      float& ca, float& cb, float& cc,
                                      float& lam)
{
    const float W = (float)IMG, H = (float)IMG;
    const float tanfov = 0.5773502691896258f;        // tan(FOV/2)
    const float focal_x = W / (2.0f * tanfov);
    const float focal_y = H / (2.0f * tanfov);
    const float lim = 1.3f * tanfov;

    float mx = means[3 * i + 0], my = means[3 * i + 1], mz = means[3 * i + 2];

    float tx = vm[0] * mx + vm[1] * my + vm[2]  * mz + vm[3];
    float ty = vm[4] * mx + vm[5] * my + vm[6]  * mz + vm[7];
    float tz = vm[8] * mx + vm[9] * my + vm[10] * mz + vm[11];
    depth = tz;

    float ph0 = pm[0]  * mx + pm[1]  * my + pm[2]  * mz + pm[3];
    float ph1 = pm[4]  * mx + pm[5]  * my + pm[6]  * mz + pm[7];
    float pw  = pm[12] * mx + pm[13] * my + pm[14] * mz + pm[15];
    float rinv = 1.0f / (pw + 1e-7f);
    px = ((ph0 * rinv + 1.0f) * W - 1.0f) * 0.5f;
    py = ((ph1 * rinv + 1.0f) * H - 1.0f) * 0.5f;

    float qw = rots[4 * i + 0], qx = rots[4 * i + 1], qy = rots[4 * i + 2], qz = rots[4 * i + 3];
    float qn = sqrtf(qw * qw + qx * qx + qy * qy + qz * qz);
    qw /= qn; qx /= qn; qy /= qn; qz /= qn;
    float R00 = 1.0f - 2.0f * (qy * qy + qz * qz), R01 = 2.0f * (qx * qy - qw * qz), R02 = 2.0f * (qx * qz + qw * qy);
    float R10 = 2.0f * (qx * qy + qw * qz), R11 = 1.0f - 2.0f * (qx * qx + qz * qz), R12 = 2.0f * (qy * qz - qw * qx);
    float R20 = 2.0f * (qx * qz - qw * qy), R21 = 2.0f * (qy * qz + qw * qx), R22 = 1.0f - 2.0f * (qx * qx + qy * qy);

    float sx = scales[3 * i + 0], sy = scales[3 * i + 1], sz = scales[3 * i + 2];
    float M00 = R00 * sx, M01 = R01 * sy, M02 = R02 * sz;
    float M10 = R10 * sx, M11 = R11 * sy, M12 = R12 * sz;
    float M20 = R20 * sx, M21 = R21 * sy, M22 = R22 * sz;
    float S00 = M00 * M00 + M01 * M01 + M02 * M02;
    float S01 = M00 * M10 + M01 * M11 + M02 * M12;
    float S02 = M00 * M20 + M01 * M21 + M02 * M22;
    float S11 = M10 * M10 + M11 * M11 + M12 * M12;
    float S12 = M10 * M20 + M11 * M21 + M12 * M22;
    float S22 = M20 * M20 + M21 * M21 + M22 * M22;

    float txc = fminf(fmaxf(tx / tz, -lim), lim) * tz;
    float tyc = fminf(fmaxf(ty / tz, -lim), lim) * tz;
    float J00 = focal_x / tz, J02 = -focal_x * txc / (tz * tz);
    float J11 = focal_y / tz, J12 = -focal_y * tyc / (tz * tz);

    float T00 = J00 * vm[0] + J02 * vm[8];
    float T01 = J00 * vm[1] + J02 * vm[9];
    float T02 = J00 * vm[2] + J02 * vm[10];
    float T10 = J11 * vm[4] + J12 * vm[8];
    float T11 = J11 * vm[5] + J12 * vm[9];
    float T12 = J11 * vm[6] + J12 * vm[10];

    float U00 = T00 * S00 + T01 * S01 + T02 * S02;
    float U01 = T00 * S01 + T01 * S11 + T02 * S12;
    float U02 = T00 * S02 + T01 * S12 + T02 * S22;
    float U10 = T10 * S00 + T11 * S01 + T12 * S02;
    float U11 = T10 * S01 + T11 * S11 + T12 * S12;
    float U12 = T10 * S02 + T11 * S12 + T12 * S22;
    float C00 = U00 * T00 + U01 * T01 + U02 * T02;
    float C01 = U00 * T10 + U01 * T11 + U02 * T12;
    float C11 = U10 * T10 + U11 * T11 + U12 * T12;

    float a = C00 + 0.3f, b = C01, c = C11 + 0.3f;
    float det = a * c - b * b;
    valid = (depth > 0.2f) && (det > 0.0f);
    float det_s = valid ? det : 1.0f;
    ca = c / det_s; cb = -b / det_s; cc = a / det_s;

    float mid = 0.5f * (a + c);
    lam = mid + sqrtf(fmaxf(mid * mid - det, 0.1f));
}

// ------------------------------------------- fused preprocess + rank + scatter
__global__ void gsplat_prep_rank_scatter(const float* __restrict__ means,
                                         const float* __restrict__ feats,
                                         const float* __restrict__ ops,
                                         const float* __restrict__ scales,
                                         const float* __restrict__ rots,
                                         const float* __restrict__ vm,
                                         const float* __restrict__ pm,
                                         float* __restrict__ gS,
                                         float4* __restrict__ culls,
                                         float* __restrict__ radii_out,
                                         int P)
{
    __shared__ unsigned int sk[SORT_N];
    __shared__ int partial[256];
    int tid = threadIdx.x;

    // Phase A: depth-only sort keys. valid == depth>0.2 (det>0 always:
    // det = (C00+.3)(C11+.3)-C01^2 >= .3(C00+C11)+.09, cov2d PSD; margin
    // ~1e3 vs fp32 error ~1e-3 -- holds in the reference too).
    #pragma unroll 2
    for (int j = tid; j < SORT_N; j += 256) {
        unsigned int key = 0xFFFFFFFFu;                  // pad sorts last
        if (j < P) {
            float mx = means[3 * j + 0], my = means[3 * j + 1], mz = means[3 * j + 2];
            float tz = vm[8] * mx + vm[9] * my + vm[10] * mz + vm[11];
            key = (tz > 0.2f) ? __float_as_uint(tz) : 0x7f800000u; // +inf invalid
        }
        sk[j] = key;
    }
    __syncthreads();

    // Phase B: stable rank for this block's 64 gaussians (4 key-slices x 64).
    int g = tid & 63, s = tid >> 6;
    int i = blockIdx.x * 64 + g;
    bool act = (i < P);
    unsigned int ki = act ? sk[i] : 0u;

    const int SLICE = SORT_N / 4;
    int j0 = s * SLICE;
    const uint4* sk4 = (const uint4*)(sk + j0);
    int r = 0;
    #pragma unroll 4
    for (int q = 0; q < SLICE / 4; ++q) {
        uint4 k = sk4[q];                                // wave-broadcast
        int j = j0 + 4 * q;
        r += (k.x < ki) || (k.x == ki && (j + 0) < i);
        r += (k.y < ki) || (k.y == ki && (j + 1) < i);
        r += (k.z < ki) || (k.z == ki && (j + 2) < i);
        r += (k.w < ki) || (k.w == ki && (j + 3) < i);
    }
    partial[tid] = r;
    __syncthreads();

    // Phase C: full record for own gaussian -> sorted slot; radii in orig order.
    if (s == 0 && act) {
        int rank = partial[g] + partial[64 + g] + partial[128 + g] + partial[192 + g];

        float depth, px, py, ca, cb, cc, lam; bool valid;
        gproj(i, means, rots, scales, vm, pm, depth, valid, px, py, ca, cb, cc, lam);

        const float SH_C0 = 0.28209479177387814f;
        float colr = fmaxf(SH_C0 * feats[3 * i + 0] + 0.5f, 0.0f);
        float colg = fmaxf(SH_C0 * feats[3 * i + 1] + 0.5f, 0.0f);
        float colb = fmaxf(SH_C0 * feats[3 * i + 2] + 0.5f, 0.0f);

        float opv = ops[i];
        float r2;
        if (valid) {
            // alpha >= 1/255 requires d^2 <= 2*lam_max*ln(255*op) (exact bound)
            r2 = 2.0f * lam * __logf(255.0f * opv) * 1.02f + 0.5f;
        } else {
            px = 0.0f; py = 0.0f; ca = 0.0f; cb = 0.0f; cc = 0.0f;
            opv = 0.0f; r2 = -1.0f;                      // never composited
        }
        radii_out[i] = valid ? ceilf(3.0f * sqrtf(lam)) : 0.0f;

        float4* dst = (float4*)(gS + (size_t)rank * GS);
        dst[0] = make_float4(px, py, ca, cb);
        dst[1] = make_float4(cc, opv, colr, colg);
        dst[2] = make_float4(colb, r2, 0.0f, 0.0f);
        culls[rank] = make_float4(px, py, r2, 0.0f);     // compact cull record
    }
}

// ----------------------------------------------------------------- raster
// Block = (tile, chunk): 64 tiles x KCH=16 chunks = 1024 blocks (4/CU).
// Wave-parallel ballot cull (2 explicit 64-wide groups, loads issued up
// front), then a 4-wide unrolled bit-loop: up to 4 hit records load
// independently, alphas compute in parallel (T-independent), T-updates
// apply in exact front-to-back order.
__global__ void __launch_bounds__(256, 4)
gsplat_raster_chunk(const float* __restrict__ gS,
                    const float4* __restrict__ culls,
                    int P, float4* __restrict__ part)
{
    int tid = threadIdx.x;
    int lx = tid & 15, ly = tid >> 4;
    int lane = tid & 63;
    int tilex = blockIdx.x & 7, tiley = blockIdx.x >> 3;
    int x = tilex * 16 + lx, y = tiley * 16 + ly;
    float gx = (float)x, gy = (float)y;
    float tx0 = (float)(tilex * 16), tx1 = (float)(tilex * 16 + 15);
    float ty0 = (float)(tiley * 16), ty1 = (float)(tiley * 16 + 15);

    int base = blockIdx.y * CHUNK;
    int cnt = min(CHUNK, P - base);

    float T = 1.0f, cr = 0.0f, cg = 0.0f, cb = 0.0f;
    const float* Gp = gS + (size_t)base * GS;

    // Both cull loads issue immediately (independent).
    float4 cu0 = culls[base + lane];
    float4 cu1 = culls[base + 64 + lane];

    #pragma unroll
    for (int half = 0; half < 2; ++half) {
        int h = half * 64;
        float4 cu = (half == 0) ? cu0 : cu1;
        bool pred = false;
        if (h + lane < cnt) {
            float ddx = cu.x - fminf(fmaxf(cu.x, tx0), tx1);
            float ddy = cu.y - fminf(fmaxf(cu.y, ty0), ty1);
            pred = (ddx * ddx + ddy * ddy <= cu.z);
        }
        unsigned long long m = __ballot(pred);           // wave-uniform mask
        while (m) {
            // Extract up to 4 hits; duplicate last index for lanes n..3
            // (their updates are guarded out below).
            int b0 = __builtin_ctzll(m); m &= m - 1;
            int n = 1, b1 = b0, b2 = b0, b3 = b0;
            if (m) { b1 = __builtin_ctzll(m); m &= m - 1; n = 2;
                if (m) { b2 = __builtin_ctzll(m); m &= m - 1; n = 3;
                    if (m) { b3 = __builtin_ctzll(m); m &= m - 1; n = 4; } } }

            // Independent record loads (wave-uniform addresses).
            const float4* R0 = (const float4*)(Gp + (size_t)(h + b0) * GS);
            const float4* R1 = (const float4*)(Gp + (size_t)(h + b1) * GS);
            const float4* R2 = (const float4*)(Gp + (size_t)(h + b2) * GS);
            const float4* R3 = (const float4*)(Gp + (size_t)(h + b3) * GS);
            float4 A0 = R0[0], B0 = R0[1], C0 = R0[2];
            float4 A1 = R1[0], B1 = R1[1], C1 = R1[2];
            float4 A2 = R2[0], B2 = R2[1], C2 = R2[2];
            float4 A3 = R3[0], B3 = R3[1], C3 = R3[2];

            // Alphas in parallel (independent of T).
            float dx0 = gx - A0.x, dy0 = gy - A0.y;
            float p0 = -0.5f * (A0.z * dx0 * dx0 + B0.x * dy0 * dy0) - A0.w * dx0 * dy0;
            float a0 = fminf(0.99f, B0.y * __expf(fminf(p0, 0.0f)));
            a0 = (p0 > 0.0f) ? 0.0f : a0;
            a0 = (a0 < 0.00392156862745098f) ? 0.0f : a0;

            float dx1 = gx - A1.x, dy1 = gy - A1.y;
            float p1 = -0.5f * (A1.z * dx1 * dx1 + B1.x * dy1 * dy1) - A1.w * dx1 * dy1;
            float a1 = fminf(0.99f, B1.y * __expf(fminf(p1, 0.0f)));
            a1 = (p1 > 0.0f) ? 0.0f : a1;
            a1 = (a1 < 0.00392156862745098f) ? 0.0f : a1;

            float dx2 = gx - A2.x, dy2 = gy - A2.y;
            float p2 = -0.5f * (A2.z * dx2 * dx2 + B2.x * dy2 * dy2) - A2.w * dx2 * dy2;
            float a2 = fminf(0.99f, B2.y * __expf(fminf(p2, 0.0f)));
            a2 = (p2 > 0.0f) ? 0.0f : a2;
            a2 = (a2 < 0.00392156862745098f) ? 0.0f : a2;

            float dx3 = gx - A3.x, dy3 = gy - A3.y;
            float p3 = -0.5f * (A3.z * dx3 * dx3 + B3.x * dy3 * dy3) - A3.w * dx3 * dy3;
            float a3 = fminf(0.99f, B3.y * __expf(fminf(p3, 0.0f)));
            a3 = (p3 > 0.0f) ? 0.0f : a3;
            a3 = (a3 < 0.00392156862745098f) ? 0.0f : a3;

            // Ordered T-updates (exact sequential semantics). n is
            // wave-uniform, so the guards are scalar branches.
            float w;
            w = T * a0; cr = fmaf(w, B0.z, cr); cg = fmaf(w, B0.w, cg); cb = fmaf(w, C0.x, cb); T *= (1.0f - a0);
            if (n > 1) { w = T * a1; cr = fmaf(w, B1.z, cr); cg = fmaf(w, B1.w, cg); cb = fmaf(w, C1.x, cb); T *= (1.0f - a1); }
            if (n > 2) { w = T * a2; cr = fmaf(w, B2.z, cr); cg = fmaf(w, B2.w, cg); cb = fmaf(w, C2.x, cb); T *= (1.0f - a2); }
            if (n > 3) { w = T * a3; cr = fmaf(w, B3.z, cr); cg = fmaf(w, B3.w, cg); cb = fmaf(w, C3.x, cb); T *= (1.0f - a3); }
        }
    }

    int pix = y * IMG + x;
    part[(size_t)blockIdx.y * NPIX + pix] = make_float4(cr, cg, cb, T);
}

// ----------------------------------------------------------------- combine
// Ordered front-to-back merge of KCH chunk partials per pixel; adds T_final.
// 16 independent loads fully unrolled; fold chain is cheap fma.
__global__ void gsplat_combine(const float4* __restrict__ part,
                               float* __restrict__ img)
{
    int pix = blockIdx.x * blockDim.x + threadIdx.x;
    if (pix >= NPIX) return;
    float4 v[KCH];
    #pragma unroll
    for (int c = 0; c < KCH; ++c)
        v[c] = part[(size_t)c * NPIX + pix];             // independent loads
    float T = 1.0f, r = 0.0f, g = 0.0f, b = 0.0f;
    #pragma unroll
    for (int c = 0; c < KCH; ++c) {
        r = fmaf(T, v[c].x, r);
        g = fmaf(T, v[c].y, g);
        b = fmaf(T, v[c].z, b);
        T *= v[c].w;
    }
    img[pix]            = r + T;
    img[NPIX + pix]     = g + T;
    img[2 * NPIX + pix] = b + T;
}

// ------------------------------------------------------------------ launch
extern "C" void kernel_launch(void* const* d_in, const int* in_sizes, int n_in,
                              void* d_out, int out_size, void* d_ws, size_t ws_size,
                              hipStream_t stream)
{
    const float* means  = (const float*)d_in[0];
    const float* feats  = (const float*)d_in[2];
    const float* ops    = (const float*)d_in[3];
    const float* scales = (const float*)d_in[4];
    const float* rots   = (const float*)d_in[5];
    const float* vm     = (const float*)d_in[6];
    const float* pm     = (const float*)d_in[7];

    int P = in_sizes[0] / 3;   // 2048

    float* img   = (float*)d_out;            // 3*128*128
    float* radii = (float*)d_out + 3 * NPIX; // P

    float*  gS    = (float*)d_ws;                        // SORT_N*GS floats
    float4* culls = (float4*)(gS + (size_t)SORT_N * GS); // SORT_N float4
    float4* part  = culls + SORT_N;                      // KCH*NPIX float4

    gsplat_prep_rank_scatter<<<(P + 63) / 64, 256, 0, stream>>>(
        means, feats, ops, scales, rots, vm, pm, gS, culls, radii, P);

    gsplat_raster_chunk<<<dim3(64, KCH), 256, 0, stream>>>(gS, culls, P, part);

    gsplat_combine<<<NPIX / 256, 256, 0, stream>>>(part, img);
}